// Round 2
// baseline (10918.082 us; speedup 1.0000x reference)
//
#include <hip/hip_runtime.h>
#include <hip/hip_bf16.h>
#include <cstdint>
#include <cstddef>

// Problem constants
#define L_    6
#define NTOK  4096      // B*T*H*W = 2*8*16*16
#define HIDP  2816      // HID=2730 padded to 44*64

typedef __bf16 bf16x8 __attribute__((ext_vector_type(8)));
typedef float  f32x4  __attribute__((ext_vector_type(4)));

__device__ __forceinline__ float bf2f(uint16_t u) {
  union { uint32_t i; float f; } v; v.i = ((uint32_t)u) << 16; return v.f;
}
__device__ __forceinline__ uint16_t f2bf(float f) {
  __hip_bfloat16 h = __float2bfloat16(f);
  return __builtin_bit_cast(uint16_t, h);
}

// ---------------- weight convert + transpose (fp32 [K][N] -> bf16 [Nd][Kd], zero-padded) ---
__global__ __launch_bounds__(256) void convt_k(const float* __restrict__ src,
                                               uint16_t* __restrict__ dst,
                                               int K, int N, int Kd, int Nd) {
  __shared__ float t[32][33];
  const int k0 = blockIdx.x * 32, n0 = blockIdx.y * 32;
  const int tx = threadIdx.x & 31, ty = threadIdx.x >> 5;   // 32 x 8
#pragma unroll
  for (int i = 0; i < 32; i += 8) {
    int k = k0 + ty + i, n = n0 + tx;
    t[ty + i][tx] = (k < K && n < N) ? src[(size_t)k * N + n] : 0.f;
  }
  __syncthreads();
#pragma unroll
  for (int i = 0; i < 32; i += 8) {
    int n = n0 + ty + i, k = k0 + tx;
    if (n < Nd && k < Kd) dst[(size_t)n * Kd + k] = f2bf(t[tx][ty + i]);
  }
}

// ---------------- embedding -----------------------------------------------------------
__global__ __launch_bounds__(256) void action_embed_k(const float* __restrict__ act,
                                                      const float* __restrict__ Wae,
                                                      const float* __restrict__ bae,
                                                      float* __restrict__ aout) {
  int bt = blockIdx.x;          // 16
  int d0 = threadIdx.x * 4;
  float r[4] = {bae[d0], bae[d0 + 1], bae[d0 + 2], bae[d0 + 3]};
#pragma unroll
  for (int c = 0; c < 8; ++c) {
    float av = act[bt * 8 + c];
    const float* wr = Wae + c * 1024 + d0;
    r[0] += av * wr[0]; r[1] += av * wr[1]; r[2] += av * wr[2]; r[3] += av * wr[3];
  }
#pragma unroll
  for (int i = 0; i < 4; ++i)
    aout[bt * 1024 + d0 + i] = r[i] / (1.f + __expf(-r[i]));
}

__global__ __launch_bounds__(256) void embed_k(const float* __restrict__ lat,
                                               const float* __restrict__ Wlp,
                                               const float* __restrict__ blp,
                                               const float* __restrict__ aemb,
                                               float* __restrict__ x) {
  int idx = blockIdx.x * 256 + threadIdx.x;   // over 4096*1024
  int tok = idx >> 10, d = idx & 1023;
  float v = blp[d] + aemb[(tok >> 8) * 1024 + d];
  const float* lr = lat + tok * 5;
#pragma unroll
  for (int c = 0; c < 5; ++c) v += lr[c] * Wlp[c * 1024 + d];
  x[idx] = v;
}

// ---------------- rmsnorm (fp32 in, bf16 out) -----------------------------------------
__global__ __launch_bounds__(256) void rmsnorm_k(const float* __restrict__ x,
                                                 const float* __restrict__ w,
                                                 uint16_t* __restrict__ out) {
  const int tok = blockIdx.x, tid = threadIdx.x;
  const float* xr = x + ((size_t)tok << 10);
  float4 v = *(const float4*)(xr + tid * 4);
  float ss = v.x * v.x + v.y * v.y + v.z * v.z + v.w * v.w;
#pragma unroll
  for (int o = 1; o < 64; o <<= 1) ss += __shfl_xor(ss, o, 64);
  __shared__ float ws4[4];
  if ((tid & 63) == 0) ws4[tid >> 6] = ss;
  __syncthreads();
  float tot = ws4[0] + ws4[1] + ws4[2] + ws4[3];
  float rs = rsqrtf(tot * (1.0f / 1024.0f) + 1e-6f);
  float4 wv = *(const float4*)(w + tid * 4);
  uint32_t p0 = (uint32_t)f2bf(v.x * rs * wv.x) | ((uint32_t)f2bf(v.y * rs * wv.y) << 16);
  uint32_t p1 = (uint32_t)f2bf(v.z * rs * wv.z) | ((uint32_t)f2bf(v.w * rs * wv.w) << 16);
  uint2 u; u.x = p0; u.y = p1;
  *(uint2*)(out + ((size_t)tok << 10) + tid * 4) = u;
}

__global__ __launch_bounds__(256) void final_norm_k(const float* __restrict__ x,
                                                    const float* __restrict__ w,
                                                    float* __restrict__ out) {
  const int bhw = blockIdx.x, tid = threadIdx.x;       // 512 blocks
  const int b = bhw >> 8, hw = bhw & 255;
  const int tok = b * 2048 + 7 * 256 + hw;
  const float* xr = x + ((size_t)tok << 10);
  float4 v = *(const float4*)(xr + tid * 4);
  float ss = v.x * v.x + v.y * v.y + v.z * v.z + v.w * v.w;
#pragma unroll
  for (int o = 1; o < 64; o <<= 1) ss += __shfl_xor(ss, o, 64);
  __shared__ float ws4[4];
  if ((tid & 63) == 0) ws4[tid >> 6] = ss;
  __syncthreads();
  float tot = ws4[0] + ws4[1] + ws4[2] + ws4[3];
  float rs = rsqrtf(tot * (1.0f / 1024.0f) + 1e-6f);
  float4 wv = *(const float4*)(w + tid * 4);
  float4 o4;
  o4.x = v.x * rs * wv.x; o4.y = v.y * rs * wv.y;
  o4.z = v.z * rs * wv.z; o4.w = v.w * rs * wv.w;
  *(float4*)(out + ((size_t)bhw << 10) + tid * 4) = o4;
}

// ---------------- MFMA GEMM: C[M,N] = A[M,K](bf16) @ Bt[N,K]^T(bf16) ------------------
// 128x128 tile, BK=64, 4 waves (2x2), each wave 64x64 via 4x4 16x16x32 MFMAs.
template <int ADD>
__global__ __launch_bounds__(256) void gemm_bt(const uint16_t* __restrict__ A,
                                               const uint16_t* __restrict__ Bt,
                                               const float* __restrict__ Res,
                                               float* __restrict__ Cf,
                                               uint16_t* __restrict__ Cb,
                                               int M, int N, int K) {
  __shared__ __align__(16) uint16_t As[128 * 64];
  __shared__ __align__(16) uint16_t Bs[128 * 64];
  const int tid = threadIdx.x;
  const int lane = tid & 63;
  const int wid = tid >> 6;
  const int wm = wid >> 1, wn = wid & 1;
  f32x4 acc[4][4] = {};
  const char* Abase = (const char*)(A + (size_t)blockIdx.x * 128 * K);
  const char* Bbase = (const char*)(Bt + (size_t)blockIdx.y * 128 * K);
  const int rowstride = K * 2;
  const int lin0 = lane * 16;

  for (int k0 = 0; k0 < K; k0 += 64) {
#pragma unroll
    for (int i = 0; i < 4; ++i) {
      int off = (i * 4 + wid) * 1024 + lin0;    // byte offset in 16KB tile
      int row = off >> 7, kb = off & 127;       // 128B per row (64 bf16)
      uint4 va = *(const uint4*)(Abase + (size_t)row * rowstride + k0 * 2 + kb);
      uint4 vb = *(const uint4*)(Bbase + (size_t)row * rowstride + k0 * 2 + kb);
      *(uint4*)((char*)As + off) = va;
      *(uint4*)((char*)Bs + off) = vb;
    }
    __syncthreads();
#pragma unroll
    for (int kk = 0; kk < 2; ++kk) {
      const int kbase = kk * 32 + (lane >> 4) * 8;
      bf16x8 af[4], bfm[4];
#pragma unroll
      for (int m = 0; m < 4; ++m)
        af[m] = *(const bf16x8*)(As + (wm * 64 + m * 16 + (lane & 15)) * 64 + kbase);
#pragma unroll
      for (int n = 0; n < 4; ++n)
        bfm[n] = *(const bf16x8*)(Bs + (wn * 64 + n * 16 + (lane & 15)) * 64 + kbase);
#pragma unroll
      for (int m = 0; m < 4; ++m)
#pragma unroll
        for (int n = 0; n < 4; ++n)
          acc[m][n] = __builtin_amdgcn_mfma_f32_16x16x32_bf16(af[m], bfm[n], acc[m][n], 0, 0, 0);
    }
    __syncthreads();
  }

  const int r0 = blockIdx.x * 128 + wm * 64 + (lane >> 4) * 4;
  const int c0 = blockIdx.y * 128 + wn * 64 + (lane & 15);
#pragma unroll
  for (int m = 0; m < 4; ++m)
#pragma unroll
    for (int n = 0; n < 4; ++n)
#pragma unroll
      for (int j = 0; j < 4; ++j) {
        int r = r0 + m * 16 + j;
        int c = c0 + n * 16;
        size_t idx = (size_t)r * N + c;
        float v = acc[m][n][j];
        if (ADD) Cf[idx] = Res[idx] + v;
        else     Cb[idx] = f2bf(v);
      }
}

// ---------------- RoPE + scatter into head-major / tile-major layouts (bf16 out) ------
// Rows: global: (b*8+g)*2048 + s (s = t*256+h*16+w), heads 0..7
//        local: 32768 + ((b*4+n)*8 + l)*512 + (t*64 + (h&7)*8 + (w&7)), heads 8..15
__global__ __launch_bounds__(256) void rope_k(const uint16_t* __restrict__ lin,
                                              uint16_t* __restrict__ qh,
                                              uint16_t* __restrict__ kh,
                                              uint16_t* __restrict__ vh) {
  int idx = blockIdx.x * 256 + threadIdx.x;     // 4096*16*32
  int pair = idx & 31;
  int nh = (idx >> 5) & 15;
  int tok = idx >> 9;
  int rem = tok & 2047;
  int b = tok >> 11;
  int t = rem >> 8, hh = (rem >> 4) & 15, ww = rem & 15;
  float p; int il, half2, segoff;
  if (pair < 8)       { p = (float)t;  il = pair;      half2 = 8;  segoff = 0; }
  else if (pair < 20) { p = (float)hh; il = pair - 8;  half2 = 12; segoff = 16; }
  else                { p = (float)ww; il = pair - 20; half2 = 12; segoff = 40; }
  float freq = __expf(-(float)il * (9.210340371976184f / (float)half2));  // BASE^(-il/half)
  float ang = p * freq;
  float sn, cs; __sincosf(ang, &sn, &cs);
  int d1 = segoff + 2 * il;
  size_t base = (size_t)tok * 3072 + nh * 64 + d1;
  float q1 = bf2f(lin[base]),        q2 = bf2f(lin[base + 1]);
  float k1 = bf2f(lin[base + 1024]), k2 = bf2f(lin[base + 1025]);
  size_t orow;
  if (nh < 8) {
    orow = ((size_t)((b << 3) + nh) << 11) + rem;
  } else {
    int n = ((hh >> 3) << 1) + (ww >> 3);
    int st = (t << 6) + ((hh & 7) << 3) + (ww & 7);
    orow = 32768 + (((size_t)((((b << 2) + n) << 3) + (nh - 8)) << 9) + st);
  }
  uint32_t qp = (uint32_t)f2bf(q1 * cs - q2 * sn) | ((uint32_t)f2bf(q1 * sn + q2 * cs) << 16);
  uint32_t kp = (uint32_t)f2bf(k1 * cs - k2 * sn) | ((uint32_t)f2bf(k1 * sn + k2 * cs) << 16);
  uint32_t vp = *(const uint32_t*)(lin + base + 2048);
  *(uint32_t*)(qh + (orow << 6) + d1) = qp;
  *(uint32_t*)(kh + (orow << 6) + d1) = kp;
  *(uint32_t*)(vh + (orow << 6) + d1) = vp;
}

// ---------------- fused flash attention (vector ALU, LDS-broadcast K/V, bf16 in) ------
__global__ __launch_bounds__(128) void flash_attn_k(const uint16_t* __restrict__ qh,
                                                    const uint16_t* __restrict__ kh,
                                                    const uint16_t* __restrict__ vh,
                                                    uint16_t* __restrict__ ocat) {
  __shared__ float Ks[64][64];
  __shared__ float Vs[64][64];
  const int tid = threadIdx.x;
  const int row = blockIdx.x * 128 + tid;       // 65536 rows
  const bool isg = row < 32768;
  int grp, seqlen; size_t kvoff;
  if (isg) { grp = row >> 11; seqlen = 2048; kvoff = (size_t)grp << 17; }
  else     { grp = (row - 32768) >> 9; seqlen = 512; kvoff = ((size_t)32768 << 6) + ((size_t)grp << 15); }
  const uint16_t* kb = kh + kvoff;
  const uint16_t* vb = vh + kvoff;
  float q[64];
  {
    const uint16_t* qr = qh + ((size_t)row << 6);
#pragma unroll
    for (int i = 0; i < 8; ++i) {
      uint4 u = *(const uint4*)(qr + i * 8);
      q[i * 8 + 0] = bf2f((uint16_t)(u.x & 0xffff)) * 0.125f;
      q[i * 8 + 1] = bf2f((uint16_t)(u.x >> 16)) * 0.125f;
      q[i * 8 + 2] = bf2f((uint16_t)(u.y & 0xffff)) * 0.125f;
      q[i * 8 + 3] = bf2f((uint16_t)(u.y >> 16)) * 0.125f;
      q[i * 8 + 4] = bf2f((uint16_t)(u.z & 0xffff)) * 0.125f;
      q[i * 8 + 5] = bf2f((uint16_t)(u.z >> 16)) * 0.125f;
      q[i * 8 + 6] = bf2f((uint16_t)(u.w & 0xffff)) * 0.125f;
      q[i * 8 + 7] = bf2f((uint16_t)(u.w >> 16)) * 0.125f;
    }
  }
  float mx = -1e30f, l = 0.f;
  float acc[64];
#pragma unroll
  for (int d = 0; d < 64; ++d) acc[d] = 0.f;

  for (int kt = 0; kt < seqlen; kt += 64) {
    __syncthreads();
#pragma unroll
    for (int it = 0; it < 4; ++it) {
      int idx = it * 128 + tid;                 // 512 chunks of 8 elements
      int r = idx >> 3, c = (idx & 7) * 8;
      uint4 ku = *(const uint4*)(kb + (((size_t)(kt + r)) << 6) + c);
      uint4 vu = *(const uint4*)(vb + (((size_t)(kt + r)) << 6) + c);
      float* kd = &Ks[r][c];
      float* vd = &Vs[r][c];
      kd[0] = bf2f((uint16_t)(ku.x & 0xffff)); kd[1] = bf2f((uint16_t)(ku.x >> 16));
      kd[2] = bf2f((uint16_t)(ku.y & 0xffff)); kd[3] = bf2f((uint16_t)(ku.y >> 16));
      kd[4] = bf2f((uint16_t)(ku.z & 0xffff)); kd[5] = bf2f((uint16_t)(ku.z >> 16));
      kd[6] = bf2f((uint16_t)(ku.w & 0xffff)); kd[7] = bf2f((uint16_t)(ku.w >> 16));
      vd[0] = bf2f((uint16_t)(vu.x & 0xffff)); vd[1] = bf2f((uint16_t)(vu.x >> 16));
      vd[2] = bf2f((uint16_t)(vu.y & 0xffff)); vd[3] = bf2f((uint16_t)(vu.y >> 16));
      vd[4] = bf2f((uint16_t)(vu.z & 0xffff)); vd[5] = bf2f((uint16_t)(vu.z >> 16));
      vd[6] = bf2f((uint16_t)(vu.w & 0xffff)); vd[7] = bf2f((uint16_t)(vu.w >> 16));
    }
    __syncthreads();
    for (int j = 0; j < 64; ++j) {
      float s = 0.f;
#pragma unroll
      for (int i = 0; i < 16; ++i) {
        float4 kv = *(const float4*)&Ks[j][i * 4];
        s += q[i * 4 + 0] * kv.x + q[i * 4 + 1] * kv.y + q[i * 4 + 2] * kv.z + q[i * 4 + 3] * kv.w;
      }
      if (s > mx) {
        float corr = __expf(mx - s);
        l *= corr;
#pragma unroll
        for (int d = 0; d < 64; ++d) acc[d] *= corr;
        mx = s;
      }
      float pw = __expf(s - mx);
      l += pw;
#pragma unroll
      for (int i = 0; i < 16; ++i) {
        float4 vv = *(const float4*)&Vs[j][i * 4];
        acc[i * 4 + 0] += pw * vv.x; acc[i * 4 + 1] += pw * vv.y;
        acc[i * 4 + 2] += pw * vv.z; acc[i * 4 + 3] += pw * vv.w;
      }
    }
  }
  float inv = 1.f / l;
  int tok, head;
  if (isg) {
    int b = grp >> 3, g = grp & 7;
    tok = b * 2048 + (row & 2047);
    head = g;
  } else {
    int r = row - 32768;
    int gg = r >> 9;
    int b = gg >> 5, n = (gg >> 3) & 3, lh = gg & 7, st = r & 511;
    int t = st >> 6, hh = ((n >> 1) << 3) + ((st >> 3) & 7), ww = ((n & 1) << 3) + (st & 7);
    tok = b * 2048 + t * 256 + hh * 16 + ww;
    head = 8 + lh;
  }
  uint32_t* o32 = (uint32_t*)(ocat + (size_t)tok * 1024 + head * 64);
#pragma unroll
  for (int d = 0; d < 32; ++d) {
    uint32_t lo = f2bf(acc[2 * d] * inv);
    uint32_t hi = f2bf(acc[2 * d + 1] * inv);
    o32[d] = lo | (hi << 16);
  }
}

// ---------------- swiglu --------------------------------------------------------------
__global__ __launch_bounds__(256) void swiglu_k(const uint16_t* __restrict__ hwv,
                                                uint16_t* __restrict__ h2) {
  int tok = blockIdx.x;
  int n = blockIdx.y * 256 + threadIdx.x;       // < 2816
  size_t i = (size_t)tok * 5632 + n;
  float a = bf2f(hwv[i]);
  float bb = bf2f(hwv[i + 2816]);
  float si = a / (1.f + __expf(-a));
  h2[(size_t)tok * 2816 + n] = f2bf(si * bb);
}

// ---------------- launch --------------------------------------------------------------
extern "C" void kernel_launch(void* const* d_in, const int* in_sizes, int n_in,
                              void* d_out, int out_size, void* d_ws, size_t ws_size,
                              hipStream_t stream) {
  const float* latent = (const float*)d_in[0];
  const float* action = (const float*)d_in[1];
  const float* Wlp    = (const float*)d_in[2];
  const float* blp    = (const float*)d_in[3];
  const float* Wae    = (const float*)d_in[4];
  const float* bae    = (const float*)d_in[5];
  const float* norm1  = (const float*)d_in[6];
  const float* Wq     = (const float*)d_in[7];
  const float* Wk     = (const float*)d_in[8];
  const float* Wv     = (const float*)d_in[9];
  const float* Wo     = (const float*)d_in[10];
  const float* norm2  = (const float*)d_in[11];
  const float* mlpw   = (const float*)d_in[12];
  const float* mlpv   = (const float*)d_in[13];
  const float* mlpo   = (const float*)d_in[14];
  const float* normo  = (const float*)d_in[15];
  float* out = (float*)d_out;

  // Workspace layout (~145 MB total)
  char* p = (char*)d_ws;
  auto alloc = [&](size_t bytes) { char* r = p; p += (bytes + 255) & ~(size_t)255; return r; };
  uint16_t* wbuf = (uint16_t*)alloc((size_t)12845056 * 2);          // per-layer weights (bf16)
  float*    x    = (float*)   alloc((size_t)NTOK * 1024 * 4);       // residual stream
  uint16_t* xn   = (uint16_t*)alloc((size_t)NTOK * 1024 * 2);       // rmsnorm out
  uint16_t* sbA  = (uint16_t*)alloc((size_t)NTOK * 5632 * 2);       // qkv / hwv
  uint16_t* qhm  = (uint16_t*)alloc((size_t)65536 * 64 * 2);
  uint16_t* khm  = (uint16_t*)alloc((size_t)65536 * 64 * 2);
  uint16_t* vhm  = (uint16_t*)alloc((size_t)65536 * 64 * 2);
  uint16_t* sbB  = (uint16_t*)alloc((size_t)NTOK * HIDP * 2);       // ocat / h2
  float*    aemb = (float*)   alloc((size_t)16 * 1024 * 4);
  (void)ws_size; (void)in_sizes; (void)n_in; (void)out_size;

  // per-layer weight sub-offsets (elements)
  const size_t OFF_QKV = 0;
  const size_t OFF_WO  = (size_t)3072 * 1024;           // 3,145,728
  const size_t OFF_MWV = OFF_WO + (size_t)1024 * 1024;  // 4,194,304
  const size_t OFF_MO  = OFF_MWV + (size_t)5632 * 1024; // 9,961,472

  uint16_t* qkv  = sbA;
  uint16_t* hwv  = sbA;
  uint16_t* ocat = sbB;
  uint16_t* h2   = sbB;

  dim3 b256(256);
  action_embed_k<<<dim3(16), b256, 0, stream>>>(action, Wae, bae, aemb);
  embed_k<<<dim3(16384), b256, 0, stream>>>(latent, Wlp, blp, aemb, x);

  for (int i = 0; i < L_; ++i) {
    // convert this layer's weights (transposed, bf16, padded)
    convt_k<<<dim3(32, 32), b256, 0, stream>>>(Wq + (size_t)i * 1048576, wbuf + OFF_QKV,               1024, 1024, 1024, 1024);
    convt_k<<<dim3(32, 32), b256, 0, stream>>>(Wk + (size_t)i * 1048576, wbuf + OFF_QKV + 1024 * 1024, 1024, 1024, 1024, 1024);
    convt_k<<<dim3(32, 32), b256, 0, stream>>>(Wv + (size_t)i * 1048576, wbuf + OFF_QKV + 2048 * 1024, 1024, 1024, 1024, 1024);
    convt_k<<<dim3(32, 32), b256, 0, stream>>>(Wo + (size_t)i * 1048576, wbuf + OFF_WO,                1024, 1024, 1024, 1024);
    convt_k<<<dim3(32, 88), b256, 0, stream>>>(mlpw + (size_t)i * 2795520, wbuf + OFF_MWV,              1024, 2730, 1024, 2816);
    convt_k<<<dim3(32, 88), b256, 0, stream>>>(mlpv + (size_t)i * 2795520, wbuf + OFF_MWV + 2816 * 1024, 1024, 2730, 1024, 2816);
    convt_k<<<dim3(88, 32), b256, 0, stream>>>(mlpo + (size_t)i * 2795520, wbuf + OFF_MO,               2730, 1024, 2816, 1024);

    rmsnorm_k<<<dim3(4096), b256, 0, stream>>>(x, norm1 + i * 1024, xn);
    gemm_bt<0><<<dim3(32, 24), b256, 0, stream>>>(xn, wbuf + OFF_QKV, nullptr, nullptr, qkv, 4096, 3072, 1024);
    rope_k<<<dim3(8192), b256, 0, stream>>>(qkv, qhm, khm, vhm);
    flash_attn_k<<<dim3(512), dim3(128), 0, stream>>>(qhm, khm, vhm, ocat);
    gemm_bt<1><<<dim3(32, 8), b256, 0, stream>>>(ocat, wbuf + OFF_WO, x, x, nullptr, 4096, 1024, 1024);
    rmsnorm_k<<<dim3(4096), b256, 0, stream>>>(x, norm2 + i * 1024, xn);
    gemm_bt<0><<<dim3(32, 44), b256, 0, stream>>>(xn, wbuf + OFF_MWV, nullptr, nullptr, hwv, 4096, 5632, 1024);
    swiglu_k<<<dim3(4096, 11), b256, 0, stream>>>(hwv, h2);
    gemm_bt<1><<<dim3(32, 8), b256, 0, stream>>>(h2, wbuf + OFF_MO, x, x, nullptr, 4096, 1024, 2816);
  }
  final_norm_k<<<dim3(512), b256, 0, stream>>>(x, normo, out);
}